// Round 12
// baseline (235.028 us; speedup 1.0000x reference)
//
#include <hip/hip_runtime.h>

// ECT: out[b,c,r,t] = sum_{n in (b,c)} sigmoid(SCALE*(lin[r] - x[n].v[:,t])), max-normalized per (b,c).
// ROUND 11 = INSTRUMENTED (NREP=32, cancelled by normalization — r8-validated trick) version of the
// candidate hot loop: 3 split u32 LUT gathers (b32 scatter ~ conflict-free, vs b128 gather = 8-way)
// + 4 scattered ds_add_u32, ZERO transcendentals. Front-end/epilogue = r10 champion verbatim.
// FPSCALE 2^16 so 32 reps cannot overflow u32.

constexpr int T   = 64;
constexpr int RES = 64;
constexpr float RADIUS = 1.0f;
constexpr float SCALE  = 100.0f;
constexpr float LOG2E  = 1.44269504088896340736f;

#define THREADS 1024
#define WAVES   16
#define NROWS   69                 // delta rows 0..67 used (loc in [-3,64], tail at loc+3); stride 69
#define LXCAP   1040
#define WMARG   512                // speculative window margin (~5.7 sigma)
#define TK      512                // LUT rows (fractional-position quantization)
#define NREP    32                 // diagnostic repetition (cancelled by normalization)
#define FPSCALE 65536.0f           // 2^16: 32 reps * 1100 pts * 2^16 = 2.3e9 < 2^32
#define FPQ     65536u
#define FPINV   (1.0f / 65536.0f)

__global__ __launch_bounds__(THREADS) void ect_main(
    const float* __restrict__ x, const float* __restrict__ v,
    const int* __restrict__ index, const int* __restrict__ channels,
    float* __restrict__ out, int N, int ppb)
{
  __shared__ alignas(16) float lx[4160];   // compacted points (float4) / reused as fin[64][65]
  __shared__ unsigned acc[T * NROWS];      // delta accumulator [t][row], stride 69 (5 mod 32 -> 2/bank)
  __shared__ unsigned tbA[TK], tbB[TK], tbC[TK];   // split delta LUTs (d0, d1, d2)
  __shared__ int      l_cnt;
  __shared__ int      l_flag;
  __shared__ float    wmax[WAVES];
  __shared__ float    s_scale;

  const int seg  = blockIdx.x;
  const int b    = seg >> 2;     // MAX_CHANNELS == 4
  const int c    = seg & 3;
  const int tid  = threadIdx.x;
  const int lane = tid & 63;
  const int wv   = tid >> 6;

  const float S2D  = SCALE * LOG2E * (2.0f * RADIUS / (RES - 1));  // 4.58 log2-units/bin
  const float invD = (RES - 1) / (2.0f * RADIUS);                  // 31.5

  // ---- speculative window loads FIRST (HBM latency hides under zeroing/table build) ----
  const int lo_w = max(0, b * ppb - WMARG);
  const int hi_w = min(N, (b + 1) * ppb + WMARG);
  const int pt0  = lo_w + tid;
  const int pt1  = lo_w + THREADS + tid;
  int i0 = -1, c0 = -1, i1 = -1, c1 = -1;
  float x0 = 0.f, y0 = 0.f, z0 = 0.f, x1 = 0.f, y1 = 0.f, z1 = 0.f;
  if (pt0 < hi_w) {
    i0 = index[pt0]; c0 = channels[pt0];
    x0 = x[pt0 * 3 + 0]; y0 = x[pt0 * 3 + 1]; z0 = x[pt0 * 3 + 2];
  }
  if (pt1 < hi_w) {
    i1 = index[pt1]; c1 = channels[pt1];
    x1 = x[pt1 * 3 + 0]; y1 = x[pt1 * 3 + 1]; z1 = x[pt1 * 3 + 2];
  }
  const float v0 = v[0 * T + lane], v1 = v[1 * T + lane], v2 = v[2 * T + lane];

  if (tid == 0) { l_cnt = 0; l_flag = 0; }
  for (int i = tid; i < T * NROWS; i += THREADS) acc[i] = 0u;

  // ---- split delta LUT build: f=(i+0.5)/TK; s_k = 1/(1+2^(S2D*(f+1-k))), k=0,1,2 ----
  for (int i = tid; i < TK; i += THREADS) {
    const float fm = (i + 0.5f) * (1.0f / TK);
    const float e0 = __builtin_amdgcn_exp2f(S2D * (fm + 1.0f));
    const float e1 = __builtin_amdgcn_exp2f(S2D * fm);
    const float e2 = __builtin_amdgcn_exp2f(S2D * (fm - 1.0f));
    unsigned q0 = (unsigned)(FPSCALE / (1.0f + e0) + 0.5f);
    unsigned q1 = (unsigned)(FPSCALE / (1.0f + e1) + 0.5f);
    unsigned q2 = (unsigned)(FPSCALE / (1.0f + e2) + 0.5f);
    q1 = max(q1, q0); q2 = max(q2, q1);
    tbA[i] = q0;            // d0
    tbB[i] = q1 - q0;       // d1
    tbC[i] = q2 - q1;       // d2  (tail = FPQ - (d0+d1+d2))
  }
  __syncthreads();

  // ---- coverage verification from loaded boundary values ----
  if (pt0 == lo_w && lo_w > 0 && i0 >= b) atomicOr(&l_flag, 1);
  if (pt0 == hi_w - 1 && hi_w < N && i0 <= b) atomicOr(&l_flag, 1);
  if (pt1 == hi_w - 1 && hi_w < N && i1 <= b) atomicOr(&l_flag, 1);

  // ---- ballot-compact from registers ----
  {
    const bool m0 = (pt0 < hi_w) && (i0 == b) && (c0 == c);
    unsigned long long mk = __ballot(m0);
    int wc = __popcll(mk), pos = 0;
    if (lane == 0 && wc) pos = atomicAdd(&l_cnt, wc);
    pos = __shfl(pos, 0);
    if (m0) {
      int off = min(pos + __popcll(mk & ((1ull << lane) - 1ull)), LXCAP - 1);
      lx[off * 4 + 0] = x0; lx[off * 4 + 1] = y0; lx[off * 4 + 2] = z0;
    }
    const bool m1 = (pt1 < hi_w) && (i1 == b) && (c1 == c);
    mk = __ballot(m1);
    wc = __popcll(mk); pos = 0;
    if (lane == 0 && wc) pos = atomicAdd(&l_cnt, wc);
    pos = __shfl(pos, 0);
    if (m1) {
      int off = min(pos + __popcll(mk & ((1ull << lane) - 1ull)), LXCAP - 1);
      lx[off * 4 + 0] = x1; lx[off * 4 + 1] = y1; lx[off * 4 + 2] = z1;
    }
  }
  __syncthreads();

  // ---- fallback: full scan outside window if coverage failed (never for this input) ----
  if (l_flag) {
    for (int p = tid; p < N; p += THREADS) {
      const bool inw = (p >= lo_w) && (p < hi_w);
      const bool mt  = !inw && (index[p] == b) && (channels[p] == c);
      unsigned long long mk = __ballot(mt);
      int wc = __popcll(mk), pos = 0;
      if (lane == 0 && wc) pos = atomicAdd(&l_cnt, wc);
      pos = __shfl(pos, 0);
      if (mt) {
        int off = min(pos + __popcll(mk & ((1ull << lane) - 1ull)), LXCAP - 1);
        lx[off * 4 + 0] = x[p * 3 + 0]; lx[off * 4 + 1] = x[p * 3 + 1]; lx[off * 4 + 2] = x[p * 3 + 2];
      }
    }
    __syncthreads();
  }
  const int m = min(l_cnt, LXCAP);
  const float4* lx4 = (const float4*)lx;
  unsigned* const arow0 = &acc[lane * NROWS];

  // ---- hot loop (x NREP diagnostic): 1 broadcast + 3 b32 gathers + 4 scattered ds_add, 0 trans ----
  for (int rep = 0; rep < NREP; ++rep) {
    for (int j = wv; j < m; j += WAVES) {
      const float4 p  = lx4[j];
      const float  g  = fmaf(p.x, v0, fmaf(p.y, v1, p.z * v2)) * invD + invD;  // (nh+1)*31.5
      const float  gf = floorf(g);
      int fq = (int)((g - gf) * (float)TK);
      fq = min(fq, TK - 1);
      const int loc = min(max((int)gf - 1, -3), 64);     // exact rows loc..loc+2, tail loc+3
      const unsigned qa = tbA[fq];
      const unsigned qb = tbB[fq];
      const unsigned qc = tbC[fq];
      const unsigned te = FPQ - (qa + qb + qc);
      atomicAdd(&arow0[max(loc,     0)], qa);
      atomicAdd(&arow0[max(loc + 1, 0)], qb);
      atomicAdd(&arow0[max(loc + 2, 0)], qc);
      atomicAdd(&arow0[loc + 3], te);                    // tail: +1 for all r >= loc+3
    }
  }
  __syncthreads();

  // ---- epilogue (r10 verbatim): prefix over r, max-normalize, store ----
  float* fin = lx;
  #pragma unroll
  for (int u2 = 0; u2 < 4; ++u2) {
    const int t = (wv << 2) | u2;
    unsigned h = acc[t * NROWS + lane];            // lane = r
    #pragma unroll
    for (int d = 1; d < 64; d <<= 1) {
      unsigned o = __shfl_up(h, (unsigned)d);
      if (lane >= d) h += o;
    }
    fin[lane * 65 + t] = (float)h * FPINV;
  }
  __syncthreads();

  float vals[4];
  float mx = 0.0f;
  #pragma unroll
  for (int k = 0; k < 4; ++k) {
    const int r = wv + k * 16;
    vals[k] = fin[r * 65 + lane];
    mx = fmaxf(mx, vals[k]);
  }
  #pragma unroll
  for (int s = 32; s >= 1; s >>= 1) mx = fmaxf(mx, __shfl_xor(mx, s));
  if (lane == 0) wmax[wv] = mx;
  __syncthreads();
  if (tid == 0) {
    float m2 = wmax[0];
    #pragma unroll
    for (int i = 1; i < WAVES; ++i) m2 = fmaxf(m2, wmax[i]);
    s_scale = (m2 > 0.0f) ? 1.0f / m2 : 1.0f;
  }
  __syncthreads();
  const float sc = s_scale;
  float* o = out + (size_t)seg * (RES * T);
  #pragma unroll
  for (int k = 0; k < 4; ++k) o[tid + k * THREADS] = vals[k] * sc;
}

extern "C" void kernel_launch(void* const* d_in, const int* in_sizes, int n_in,
                              void* d_out, int out_size, void* d_ws, size_t ws_size,
                              hipStream_t stream) {
  const float* x        = (const float*)d_in[0];
  const float* v        = (const float*)d_in[1];
  const int*   index    = (const int*)d_in[2];
  const int*   channels = (const int*)d_in[3];
  float*       out      = (float*)d_out;
  const int N    = in_sizes[2];              // 32768
  const int nseg = out_size / (RES * T);     // 128
  const int ppb  = N / (nseg / 4);           // points per batch estimate (1024)

  hipLaunchKernelGGL(ect_main, dim3(nseg), dim3(THREADS), 0, stream,
                     x, v, index, channels, out, N, ppb);
}

// Round 13
// 13.578 us; speedup vs baseline: 17.3101x; 17.3101x over previous
//
#include <hip/hip_runtime.h>

// ECT: out[b,c,r,t] = sum_{n in (b,c)} sigmoid(SCALE*(lin[r] - x[n].v[:,t])), max-normalized per (b,c).
// r12: ONE LDS op per point (r11 counters: 7 scattered LDS ops/point @ ~6.7cy dominated).
// Hot loop: g quantized to 1/4-bin -> packed-u16 histogram hist[t][q] via single ds_add_u32.
// Reconstruction: per-t prefix-scan (saturated tail PS[4r]) + 15-tap sigmoid FIR over hist.
// Front-end (speculative window load, register ballot-compact, fallback) = r10 verbatim.

constexpr int T   = 64;
constexpr int RES = 64;
constexpr float RADIUS = 1.0f;
constexpr float SCALE  = 100.0f;
constexpr float LOG2E  = 1.44269504088896340736f;

#define THREADS 1024
#define WAVES   16
#define HSTR    137                // hist row stride in u32 (135 used: q in [0,268] packed 2/u32)
#define LXCAP   1040
#define WMARG   512                // speculative window margin (~5.7 sigma)

__global__ __launch_bounds__(THREADS) void ect_main(
    const float* __restrict__ x, const float* __restrict__ v,
    const int* __restrict__ index, const int* __restrict__ channels,
    float* __restrict__ out, int N, int ppb)
{
  __shared__ alignas(16) float lx[4160];   // compacted points (float4) / reused as PS grid fin[64][65]
  __shared__ unsigned hist[T * HSTR];      // packed u16 quarter-bin histogram [t][q>>1] (35KB)
  __shared__ int      l_cnt;
  __shared__ int      l_flag;
  __shared__ float    wmax[WAVES];
  __shared__ float    s_scale;

  const int seg  = blockIdx.x;
  const int b    = seg >> 2;     // MAX_CHANNELS == 4
  const int c    = seg & 3;
  const int tid  = threadIdx.x;
  const int lane = tid & 63;
  const int wv   = tid >> 6;

  const float S2D  = SCALE * LOG2E * (2.0f * RADIUS / (RES - 1));  // 4.58 log2-units/bin
  const float invD = (RES - 1) / (2.0f * RADIUS);                  // 31.5

  // ---- speculative window loads FIRST (HBM latency hides under zeroing) ----
  const int lo_w = max(0, b * ppb - WMARG);
  const int hi_w = min(N, (b + 1) * ppb + WMARG);
  const int pt0  = lo_w + tid;
  const int pt1  = lo_w + THREADS + tid;
  int i0 = -1, c0 = -1, i1 = -1, c1 = -1;
  float x0 = 0.f, y0 = 0.f, z0 = 0.f, x1 = 0.f, y1 = 0.f, z1 = 0.f;
  if (pt0 < hi_w) {
    i0 = index[pt0]; c0 = channels[pt0];
    x0 = x[pt0 * 3 + 0]; y0 = x[pt0 * 3 + 1]; z0 = x[pt0 * 3 + 2];
  }
  if (pt1 < hi_w) {
    i1 = index[pt1]; c1 = channels[pt1];
    x1 = x[pt1 * 3 + 0]; y1 = x[pt1 * 3 + 1]; z1 = x[pt1 * 3 + 2];
  }
  const float w0 = v[0 * T + lane] * invD;
  const float w1 = v[1 * T + lane] * invD;
  const float w2 = v[2 * T + lane] * invD;

  if (tid == 0) { l_cnt = 0; l_flag = 0; }
  for (int i = tid; i < T * HSTR; i += THREADS) hist[i] = 0u;
  __syncthreads();

  // ---- coverage verification from loaded boundary values ----
  if (pt0 == lo_w && lo_w > 0 && i0 >= b) atomicOr(&l_flag, 1);
  if (pt0 == hi_w - 1 && hi_w < N && i0 <= b) atomicOr(&l_flag, 1);
  if (pt1 == hi_w - 1 && hi_w < N && i1 <= b) atomicOr(&l_flag, 1);

  // ---- ballot-compact from registers ----
  {
    const bool m0 = (pt0 < hi_w) && (i0 == b) && (c0 == c);
    unsigned long long mk = __ballot(m0);
    int wc = __popcll(mk), pos = 0;
    if (lane == 0 && wc) pos = atomicAdd(&l_cnt, wc);
    pos = __shfl(pos, 0);
    if (m0) {
      int off = min(pos + __popcll(mk & ((1ull << lane) - 1ull)), LXCAP - 1);
      lx[off * 4 + 0] = x0; lx[off * 4 + 1] = y0; lx[off * 4 + 2] = z0;
    }
    const bool m1 = (pt1 < hi_w) && (i1 == b) && (c1 == c);
    mk = __ballot(m1);
    wc = __popcll(mk); pos = 0;
    if (lane == 0 && wc) pos = atomicAdd(&l_cnt, wc);
    pos = __shfl(pos, 0);
    if (m1) {
      int off = min(pos + __popcll(mk & ((1ull << lane) - 1ull)), LXCAP - 1);
      lx[off * 4 + 0] = x1; lx[off * 4 + 1] = y1; lx[off * 4 + 2] = z1;
    }
  }
  __syncthreads();

  // ---- fallback: full scan outside window if coverage failed (never for this input) ----
  if (l_flag) {
    for (int p = tid; p < N; p += THREADS) {
      const bool inw = (p >= lo_w) && (p < hi_w);
      const bool mt  = !inw && (index[p] == b) && (channels[p] == c);
      unsigned long long mk = __ballot(mt);
      int wc = __popcll(mk), pos = 0;
      if (lane == 0 && wc) pos = atomicAdd(&l_cnt, wc);
      pos = __shfl(pos, 0);
      if (mt) {
        int off = min(pos + __popcll(mk & ((1ull << lane) - 1ull)), LXCAP - 1);
        lx[off * 4 + 0] = x[p * 3 + 0]; lx[off * 4 + 1] = x[p * 3 + 1]; lx[off * 4 + 2] = x[p * 3 + 2];
      }
    }
    __syncthreads();
  }
  const int m = min(l_cnt, LXCAP);
  const float4* lx4 = (const float4*)lx;
  unsigned* const hrow = &hist[lane * HSTR];

  // ---- hot loop: lane = t; per point ONE ds_add_u32 into quarter-bin histogram ----
  #pragma unroll 2
  for (int j = wv; j < m; j += WAVES) {
    const float4 p = lx4[j];                                     // uniform broadcast read
    float g = fmaf(p.x, w0, fmaf(p.y, w1, p.z * w2)) + invD;     // (nh+1)*31.5
    g = fminf(fmaxf(g, -2.0f), 65.0f);
    const int q = (int)floorf(fmaf(g, 4.0f, 8.5f));              // round((g+2)*4) in [0,268]
    atomicAdd(&hrow[q >> 1], (q & 1) ? 0x10000u : 1u);
  }
  __syncthreads();

  // ---- Phase A: per-t inclusive prefix PS[4r] -> fin[r][t] (saturated-tail term) ----
  float* fin = lx;
  #pragma unroll
  for (int u = 0; u < 4; ++u) {
    const int t = (wv << 2) | u;
    const unsigned* hr = &hist[t * HSTR];
    unsigned piece;
    if (lane == 0) {
      piece = hr[0] & 0xFFFFu;                                   // q = 0
    } else {
      const unsigned a  = hr[2 * lane - 2];
      const unsigned bb = hr[2 * lane - 1];
      const unsigned cc = hr[2 * lane];
      piece = (a >> 16) + (bb & 0xFFFFu) + (bb >> 16) + (cc & 0xFFFFu);  // q in [4l-3, 4l]
    }
    #pragma unroll
    for (int d = 1; d < 64; d <<= 1) {
      unsigned o = __shfl_up(piece, (unsigned)d);
      if (lane >= d) piece += o;
    }
    fin[lane * 65 + t] = (float)piece;                           // PS[4*lane] for direction t
  }
  __syncthreads();

  // ---- Phase B: 15-tap sigmoid FIR over hist + PS -> vals; then max-normalize + store ----
  float wt[16];
  #pragma unroll
  for (int j = 1; j <= 15; ++j)
    wt[j] = __builtin_amdgcn_rcpf(1.0f + __builtin_amdgcn_exp2f((S2D * 0.25f) * (float)(j - 8)));

  float vals[4];
  float mx = 0.0f;
  #pragma unroll
  for (int k = 0; k < 4; ++k) {
    const int r = wv + (k << 4);                  // flat = tid + k*1024 -> r, t = lane
    float a = fin[r * 65 + lane];                 // PS[4r]: all q <= 4r contribute 1
    const unsigned* hb = &hist[lane * HSTR + 2 * r];
    unsigned h = hb[0];
    a = fmaf((float)(h >> 16), wt[1], a);         // q = 4r+1
    #pragma unroll
    for (int k2 = 1; k2 <= 7; ++k2) {
      h = hb[k2];
      a = fmaf((float)(h & 0xFFFFu), wt[2 * k2], a);        // q = 4r+2k2
      a = fmaf((float)(h >> 16),     wt[2 * k2 + 1], a);    // q = 4r+2k2+1
    }
    vals[k] = a;
    mx = fmaxf(mx, a);
  }

  #pragma unroll
  for (int s = 32; s >= 1; s >>= 1) mx = fmaxf(mx, __shfl_xor(mx, s));
  if (lane == 0) wmax[wv] = mx;
  __syncthreads();
  if (tid == 0) {
    float m2 = wmax[0];
    #pragma unroll
    for (int i = 1; i < WAVES; ++i) m2 = fmaxf(m2, wmax[i]);
    s_scale = (m2 > 0.0f) ? 1.0f / m2 : 1.0f;
  }
  __syncthreads();
  const float sc = s_scale;
  float* o = out + (size_t)seg * (RES * T);
  #pragma unroll
  for (int k = 0; k < 4; ++k) o[tid + k * THREADS] = vals[k] * sc;
}

extern "C" void kernel_launch(void* const* d_in, const int* in_sizes, int n_in,
                              void* d_out, int out_size, void* d_ws, size_t ws_size,
                              hipStream_t stream) {
  const float* x        = (const float*)d_in[0];
  const float* v        = (const float*)d_in[1];
  const int*   index    = (const int*)d_in[2];
  const int*   channels = (const int*)d_in[3];
  float*       out      = (float*)d_out;
  const int N    = in_sizes[2];              // 32768
  const int nseg = out_size / (RES * T);     // 128
  const int ppb  = N / (nseg / 4);           // points per batch estimate (1024)

  hipLaunchKernelGGL(ect_main, dim3(nseg), dim3(THREADS), 0, stream,
                     x, v, index, channels, out, N, ppb);
}